// Round 1
// baseline (2570.554 us; speedup 1.0000x reference)
//
#include <hip/hip_runtime.h>
#include <math.h>

// Problem constants (fixed by reference setup_inputs)
#define B   8
#define C   64
#define HH  192
#define WWD 192
#define P   (HH*WWD)     // 36864
#define NC  2
#define NS  8

// Workspace layout (float offsets)
#define OFF_SPACE 0                    // 16*8*P = 4718592 unnormalized space maps
#define OFF_S     4718592              // 128 per-map sums
#define OFF_R     4718720              // 8*16*64*9 = 73728 correlations
#define OFF_TOK2  4792448              // 8*2*64 = 1024
#define OFF_STATS 4793472              // 128 doubles (256 float slots), 8B aligned
#define OFF_SCALE 4793728              // 64
#define OFF_SHIFT 4793792              // 64
#define WS_FLOATS 4793856              // ~19.2 MB total

__device__ __forceinline__ float sigm(float x) { return 1.0f / (1.0f + expf(-x)); }

// K1: space maps (sigmoid + 1->7 ch 3x3 conv + sigmoid), unnormalized, plus per-(map,ch) sums.
__global__ void k_space(const float* __restrict__ cs, const float* __restrict__ Wc,
                        float* __restrict__ space, float* __restrict__ S) {
    int m = blockIdx.y;                       // m = b*2 + c
    int p = blockIdx.x * 256 + threadIdx.x;   // 144*256 == P exactly
    int h = p / WWD, w = p - (p / WWD) * WWD;
    float cp[9];
    #pragma unroll
    for (int ky = 0; ky < 3; ky++)
        #pragma unroll
        for (int kx = 0; kx < 3; kx++) {
            int hh = h + ky - 1, ww = w + kx - 1;
            float v = 0.f;  // zero-pad AFTER sigmoid (conv pads class_prob with 0)
            if ((unsigned)hh < HH && (unsigned)ww < WWD)
                v = sigm(cs[m * P + hh * WWD + ww]);
            cp[ky * 3 + kx] = v;
        }
    float ch[8];
    ch[0] = cp[4];
    #pragma unroll
    for (int j = 0; j < 7; j++) {
        float a = 0.f;
        #pragma unroll
        for (int k = 0; k < 9; k++) a += Wc[j * 9 + k] * cp[k];
        ch[j + 1] = sigm(a);
    }
    #pragma unroll
    for (int q = 0; q < 8; q++)
        space[(m * 8 + q) * P + p] = ch[q];
    // per-(m,ch) spatial sums: wave reduce + atomic
    #pragma unroll
    for (int q = 0; q < 8; q++) {
        float v = ch[q];
        for (int off = 32; off > 0; off >>= 1) v += __shfl_down(v, off);
        if ((threadIdx.x & 63) == 0) atomicAdd(&S[m * 8 + q], v);
    }
}

// K2: R[b,sc,i,k] = sum_p xpad[b,i,p shifted by k] * space[b,c,s,p]  (unnormalized space)
__global__ void k_R(const float* __restrict__ x, const float* __restrict__ space,
                    float* __restrict__ R) {
    int i = blockIdx.x, sc = blockIdx.y, b = blockIdx.z;   // sc = s*2 + c
    int s = sc >> 1, c = sc & 1;
    const float* xp = x + (b * C + i) * P;
    const float* sp = space + ((b * NC + c) * NS + s) * P;
    float acc[9];
    #pragma unroll
    for (int k = 0; k < 9; k++) acc[k] = 0.f;
    for (int p = threadIdx.x; p < P; p += 256) {
        int h = p / WWD, w = p - h * WWD;
        float sv = sp[p];
        #pragma unroll
        for (int ky = 0; ky < 3; ky++) {
            int hh = h + ky - 1;
            if ((unsigned)hh >= HH) continue;
            #pragma unroll
            for (int kx = 0; kx < 3; kx++) {
                int ww = w + kx - 1;
                if ((unsigned)ww >= WWD) continue;
                acc[ky * 3 + kx] += xp[hh * WWD + ww] * sv;
            }
        }
    }
    __shared__ float red[4][9];
    int lane = threadIdx.x & 63, wave = threadIdx.x >> 6;
    #pragma unroll
    for (int k = 0; k < 9; k++) {
        float v = acc[k];
        for (int off = 32; off > 0; off >>= 1) v += __shfl_down(v, off);
        if (lane == 0) red[wave][k] = v;
    }
    __syncthreads();
    if (threadIdx.x < 9) {
        float v = red[0][threadIdx.x] + red[1][threadIdx.x] +
                  red[2][threadIdx.x] + red[3][threadIdx.x];
        R[((b * 16 + sc) * 64 + i) * 9 + threadIdx.x] = v;
    }
}

// K3: tok2[b,c,d] = sum_s Wcs[s]/S[b,c,s] * sum_{i,k} Wxs[s*64+d,i,k] * R[b,s,c,i,k]
__global__ void k_tok2(const float* __restrict__ Wxs, const float* __restrict__ Wcs,
                       const float* __restrict__ R, const float* __restrict__ S,
                       float* __restrict__ tok2) {
    int bc = blockIdx.x, s = blockIdx.y;
    int b = bc >> 1, c = bc & 1;
    int d = threadIdx.x;
    const float* Rp = R + ((b * 16 + s * 2 + c) * 64) * 9;   // i*9+k contiguous
    const float* Wp = Wxs + (s * C + d) * (C * 9);           // i*9+k contiguous
    float a = 0.f;
    for (int t = 0; t < C * 9; t++) a += Wp[t] * Rp[t];
    float val = a * Wcs[s] / S[(b * NC + c) * NS + s];
    atomicAdd(&tok2[bc * C + d], val);
}

// K5: regenerate info tile from class_score + tok2 in LDS, direct 3x3 64->64 conv, y -> d_out
__launch_bounds__(256)
__global__ void k_conv(const float* __restrict__ cs, const float* __restrict__ tok2,
                       const float* __restrict__ Wcval, const float* __restrict__ Wattn,
                       const float* __restrict__ Wcomb, const float* __restrict__ Ws,
                       float* __restrict__ y) {
    int b = blockIdx.y;
    int tile = blockIdx.x;                       // 12x12 tiles of 16x16
    int ty0 = (tile / 12) * 16, tx0 = (tile % 12) * 16;
    __shared__ float g0[324], g1[324], til[324]; // 18x18 halo
    float wa[8], wt[8];
    #pragma unroll
    for (int s = 0; s < 8; s++) { wa[s] = Wcomb[s] * Wcval[s]; wt[s] = Wattn[s]; }
    for (int idx = threadIdx.x; idx < 324; idx += 256) {
        int gy = ty0 - 1 + idx / 18, gx = tx0 - 1 + idx % 18;
        float a0 = 0.f, a1 = 0.f;
        if ((unsigned)gy < HH && (unsigned)gx < WWD) {
            int p = gy * WWD + gx;
            float c0 = sigm(cs[(b * NC + 0) * P + p]);
            float c1 = sigm(cs[(b * NC + 1) * P + p]);
            #pragma unroll
            for (int s = 0; s < 8; s++) {
                a0 += wa[s] * sigm(c0 * wt[s]);
                a1 += wa[s] * sigm(c1 * wt[s]);
            }
        }
        g0[idx] = a0; g1[idx] = a1;
    }
    __syncthreads();
    float acc[64];
    #pragma unroll
    for (int o = 0; o < 64; o++) acc[o] = 0.f;
    int ty = threadIdx.x >> 4, tx = threadIdx.x & 15;
    for (int ci = 0; ci < 64; ci++) {
        float t0 = tok2[(b * NC + 0) * C + ci];   // uniform -> s_load
        float t1 = tok2[(b * NC + 1) * C + ci];
        for (int idx = threadIdx.x; idx < 324; idx += 256)
            til[idx] = g0[idx] * t0 + g1[idx] * t1;
        __syncthreads();
        float v[9];
        #pragma unroll
        for (int dy = 0; dy < 3; dy++)
            #pragma unroll
            for (int dx = 0; dx < 3; dx++)
                v[dy * 3 + dx] = til[(ty + dy) * 18 + (tx + dx)];
        #pragma unroll
        for (int oc = 0; oc < 64; oc++) {
            const float* wp = Ws + (oc * 64 + ci) * 9;   // uniform -> s_load
            float a = acc[oc];
            a += wp[0] * v[0]; a += wp[1] * v[1]; a += wp[2] * v[2];
            a += wp[3] * v[3]; a += wp[4] * v[4]; a += wp[5] * v[5];
            a += wp[6] * v[6]; a += wp[7] * v[7]; a += wp[8] * v[8];
            acc[oc] = a;
        }
        __syncthreads();
    }
    int py = ty0 + ty, px = tx0 + tx;
    #pragma unroll
    for (int oc = 0; oc < 64; oc++)
        y[(b * C + oc) * P + py * WWD + px] = acc[oc];
}

// K6: BN partial stats (fp64 accumulate) per channel
__global__ void k_stats(const float* __restrict__ y, double* __restrict__ st) {
    int ch = blockIdx.x, b = blockIdx.y;
    const float* yp = y + (b * C + ch) * P;
    double s = 0.0, s2 = 0.0;
    for (int p = threadIdx.x; p < P; p += 256) {
        double v = (double)yp[p];
        s += v; s2 += v * v;
    }
    for (int off = 32; off > 0; off >>= 1) { s += __shfl_down(s, off); s2 += __shfl_down(s2, off); }
    __shared__ double rs[4], rs2[4];
    int lane = threadIdx.x & 63, wave = threadIdx.x >> 6;
    if (lane == 0) { rs[wave] = s; rs2[wave] = s2; }
    __syncthreads();
    if (threadIdx.x == 0) {
        atomicAdd(&st[ch],      rs[0] + rs[1] + rs[2] + rs[3]);
        atomicAdd(&st[64 + ch], rs2[0] + rs2[1] + rs2[2] + rs2[3]);
    }
}

// K7: finalize BN scale/shift
__global__ void k_bnfin(const double* __restrict__ st, const float* __restrict__ gamma,
                        const float* __restrict__ beta, float* __restrict__ scale,
                        float* __restrict__ shift) {
    int c2 = threadIdx.x;
    double n = (double)(B * P);
    double mean = st[c2] / n;
    double var = st[64 + c2] / n - mean * mean;
    float sc = gamma[c2] * rsqrtf((float)var + 1e-5f);
    scale[c2] = sc;
    shift[c2] = beta[c2] - (float)mean * sc;
}

// K8: out = x + relu(y*scale+shift), in-place on d_out (y staged there), float4
__global__ void k_final(const float* __restrict__ x, const float* __restrict__ scale,
                        const float* __restrict__ shift, float* __restrict__ out) {
    int i4 = blockIdx.x * 256 + threadIdx.x;
    int base = i4 * 4;
    int ch = (base / P) % C;              // uniform per block (P % 1024 == 0)
    float sc = scale[ch], sh = shift[ch];
    float4 xv = *(const float4*)(x + base);
    float4 yv = *(float4*)(out + base);
    yv.x = fmaxf(yv.x * sc + sh, 0.f) + xv.x;
    yv.y = fmaxf(yv.y * sc + sh, 0.f) + xv.y;
    yv.z = fmaxf(yv.z * sc + sh, 0.f) + xv.z;
    yv.w = fmaxf(yv.w * sc + sh, 0.f) + xv.w;
    *(float4*)(out + base) = yv;
}

extern "C" void kernel_launch(void* const* d_in, const int* in_sizes, int n_in,
                              void* d_out, int out_size, void* d_ws, size_t ws_size,
                              hipStream_t stream) {
    const float* x     = (const float*)d_in[0];
    const float* cs    = (const float*)d_in[1];
    const float* Wc    = (const float*)d_in[2];
    const float* Wxs   = (const float*)d_in[3];
    const float* Wcsp  = (const float*)d_in[4];
    const float* Wcval = (const float*)d_in[5];
    const float* Wattn = (const float*)d_in[6];
    const float* Wcomb = (const float*)d_in[7];
    const float* Wsing = (const float*)d_in[8];
    const float* gamma = (const float*)d_in[9];
    const float* beta  = (const float*)d_in[10];
    float* ws  = (float*)d_ws;
    float* out = (float*)d_out;

    float*  space = ws + OFF_SPACE;
    float*  S     = ws + OFF_S;
    float*  R     = ws + OFF_R;
    float*  tok2  = ws + OFF_TOK2;
    double* st    = (double*)(ws + OFF_STATS);
    float*  scale = ws + OFF_SCALE;
    float*  shift = ws + OFF_SHIFT;

    // zero accumulators (S, R, tok2, stats, scale/shift) — ws is poisoned each call
    hipMemsetAsync(S, 0, (WS_FLOATS - OFF_S) * sizeof(float), stream);

    k_space<<<dim3(144, 16), 256, 0, stream>>>(cs, Wc, space, S);
    k_R    <<<dim3(64, 16, 8), 256, 0, stream>>>(x, space, R);
    k_tok2 <<<dim3(16, 8), 64, 0, stream>>>(Wxs, Wcsp, R, S, tok2);
    k_conv <<<dim3(144, 8), 256, 0, stream>>>(cs, tok2, Wcval, Wattn, Wcomb, Wsing, out);
    k_stats<<<dim3(64, 8), 256, 0, stream>>>(out, st);
    k_bnfin<<<1, 64, 0, stream>>>(st, gamma, beta, scale, shift);
    k_final<<<(B * C * P) / 1024, 256, 0, stream>>>(x, scale, shift, out);
}

// Round 2
// 1456.371 us; speedup vs baseline: 1.7650x; 1.7650x over previous
//
#include <hip/hip_runtime.h>
#include <math.h>

// Problem constants (fixed by reference setup_inputs)
#define B   8
#define C   64
#define HH  192
#define WWD 192
#define P   (HH*WWD)     // 36864
#define NC  2
#define NS  8

// Workspace layout (float offsets)
#define OFF_SPACE 0                    // 16*8*P = 4718592 unnormalized space maps
#define OFF_S     4718592              // 128 per-map sums
#define OFF_R     4718720              // 8*16*64*9 = 73728 correlations
#define OFF_TOK2  4792448              // 8*2*64 = 1024
#define OFF_STATS 4793472              // 128 doubles (256 float slots), 8B aligned
#define OFF_SCALE 4793728              // 64
#define OFF_SHIFT 4793792              // 64
#define WS_FLOATS 4793856              // ~19.2 MB total

__device__ __forceinline__ float sigm(float x) { return 1.0f / (1.0f + expf(-x)); }

// K1: space maps (sigmoid + 1->7 ch 3x3 conv + sigmoid), unnormalized, plus per-(map,ch) sums.
__global__ void k_space(const float* __restrict__ cs, const float* __restrict__ Wc,
                        float* __restrict__ space, float* __restrict__ S) {
    int m = blockIdx.y;                       // m = b*2 + c
    int p = blockIdx.x * 256 + threadIdx.x;   // 144*256 == P exactly
    int h = p / WWD, w = p - (p / WWD) * WWD;
    float cp[9];
    #pragma unroll
    for (int ky = 0; ky < 3; ky++)
        #pragma unroll
        for (int kx = 0; kx < 3; kx++) {
            int hh = h + ky - 1, ww = w + kx - 1;
            float v = 0.f;  // zero-pad AFTER sigmoid (conv pads class_prob with 0)
            if ((unsigned)hh < HH && (unsigned)ww < WWD)
                v = sigm(cs[m * P + hh * WWD + ww]);
            cp[ky * 3 + kx] = v;
        }
    float ch[8];
    ch[0] = cp[4];
    #pragma unroll
    for (int j = 0; j < 7; j++) {
        float a = 0.f;
        #pragma unroll
        for (int k = 0; k < 9; k++) a += Wc[j * 9 + k] * cp[k];
        ch[j + 1] = sigm(a);
    }
    #pragma unroll
    for (int q = 0; q < 8; q++)
        space[(m * 8 + q) * P + p] = ch[q];
    // per-(m,ch) spatial sums: wave reduce + atomic
    #pragma unroll
    for (int q = 0; q < 8; q++) {
        float v = ch[q];
        for (int off = 32; off > 0; off >>= 1) v += __shfl_down(v, off);
        if ((threadIdx.x & 63) == 0) atomicAdd(&S[m * 8 + q], v);
    }
}

// K2 (rewritten): register-tiled correlation.
// Block = (b, scg, ig): 2 space maps x 8 x-channels, full image per block.
// acc[m][i][t] += x[i][p] * space[scg*2+m][p - delta_t]   (144 FMA / 26 loads per pixel)
__launch_bounds__(256, 2)
__global__ void k_R2(const float* __restrict__ x, const float* __restrict__ space,
                     float* __restrict__ R) {
    int ig  = blockIdx.x;   // 0..7 : i = ig*8 + il
    int scg = blockIdx.y;   // 0..7 : sc = scg*2 + m
    int b   = blockIdx.z;

    const float* xb = x + (b * C + ig * 8) * P;
    // space map for sc = s*2+c lives at ((b*2+c)*8+s)*P
    const float* spb[2];
    #pragma unroll
    for (int m = 0; m < 2; m++) {
        int sc = scg * 2 + m;
        int s = sc >> 1, c = sc & 1;
        spb[m] = space + ((b * NC + c) * NS + s) * P;
    }

    float acc[2][8][9];
    #pragma unroll
    for (int m = 0; m < 2; m++)
        #pragma unroll
        for (int i = 0; i < 8; i++)
            #pragma unroll
            for (int t = 0; t < 9; t++) acc[m][i][t] = 0.f;

    for (int iter = 0; iter < P / 256; iter++) {
        int p = iter * 256 + threadIdx.x;
        int h = p / WWD, w = p - (p / WWD) * WWD;
        float xv[8];
        #pragma unroll
        for (int i = 0; i < 8; i++) xv[i] = xb[i * P + p];
        #pragma unroll
        for (int m = 0; m < 2; m++) {
            const float* sp = spb[m];
            #pragma unroll
            for (int ty = 0; ty < 3; ty++) {
                int sh = h - ty + 1;
                #pragma unroll
                for (int tx = 0; tx < 3; tx++) {
                    int sw = w - tx + 1;
                    bool ok = ((unsigned)sh < HH) & ((unsigned)sw < WWD);
                    int idx = ok ? (sh * WWD + sw) : 0;
                    float v = sp[idx];
                    v = ok ? v : 0.f;
                    #pragma unroll
                    for (int i = 0; i < 8; i++)
                        acc[m][i][ty * 3 + tx] += xv[i] * v;
                }
            }
        }
    }

    // reduce 144 partials across the block
    __shared__ float red[4][144];
    int lane = threadIdx.x & 63, wave = threadIdx.x >> 6;
    #pragma unroll
    for (int m = 0; m < 2; m++)
        #pragma unroll
        for (int i = 0; i < 8; i++)
            #pragma unroll
            for (int t = 0; t < 9; t++) {
                float v = acc[m][i][t];
                for (int off = 32; off > 0; off >>= 1) v += __shfl_down(v, off);
                if (lane == 0) red[wave][(m * 8 + i) * 9 + t] = v;
            }
    __syncthreads();
    if (threadIdx.x < 144) {
        int v_ = threadIdx.x;
        int m = v_ / 72, rem = v_ % 72;
        int i = rem / 9, t = rem % 9;
        float s = red[0][v_] + red[1][v_] + red[2][v_] + red[3][v_];
        int sc = scg * 2 + m;
        R[((b * 16 + sc) * 64 + (ig * 8 + i)) * 9 + t] = s;
    }
}

// K3: tok2[b,c,d] = sum_s Wcs[s]/S[b,c,s] * sum_{i,k} Wxs[s*64+d,i,k] * R[b,s,c,i,k]
__global__ void k_tok2(const float* __restrict__ Wxs, const float* __restrict__ Wcs,
                       const float* __restrict__ R, const float* __restrict__ S,
                       float* __restrict__ tok2) {
    int bc = blockIdx.x, s = blockIdx.y;
    int b = bc >> 1, c = bc & 1;
    int d = threadIdx.x;
    const float* Rp = R + ((b * 16 + s * 2 + c) * 64) * 9;   // i*9+k contiguous
    const float* Wp = Wxs + (s * C + d) * (C * 9);           // i*9+k contiguous
    float a = 0.f;
    for (int t = 0; t < C * 9; t++) a += Wp[t] * Rp[t];
    float val = a * Wcs[s] / S[(b * NC + c) * NS + s];
    atomicAdd(&tok2[bc * C + d], val);
}

// K5: regenerate info tile from class_score + tok2 in LDS, direct 3x3 64->64 conv, y -> d_out
__launch_bounds__(256)
__global__ void k_conv(const float* __restrict__ cs, const float* __restrict__ tok2,
                       const float* __restrict__ Wcval, const float* __restrict__ Wattn,
                       const float* __restrict__ Wcomb, const float* __restrict__ Ws,
                       float* __restrict__ y) {
    int b = blockIdx.y;
    int tile = blockIdx.x;                       // 12x12 tiles of 16x16
    int ty0 = (tile / 12) * 16, tx0 = (tile % 12) * 16;
    __shared__ float g0[324], g1[324], til[324]; // 18x18 halo
    float wa[8], wt[8];
    #pragma unroll
    for (int s = 0; s < 8; s++) { wa[s] = Wcomb[s] * Wcval[s]; wt[s] = Wattn[s]; }
    for (int idx = threadIdx.x; idx < 324; idx += 256) {
        int gy = ty0 - 1 + idx / 18, gx = tx0 - 1 + idx % 18;
        float a0 = 0.f, a1 = 0.f;
        if ((unsigned)gy < HH && (unsigned)gx < WWD) {
            int p = gy * WWD + gx;
            float c0 = sigm(cs[(b * NC + 0) * P + p]);
            float c1 = sigm(cs[(b * NC + 1) * P + p]);
            #pragma unroll
            for (int s = 0; s < 8; s++) {
                a0 += wa[s] * sigm(c0 * wt[s]);
                a1 += wa[s] * sigm(c1 * wt[s]);
            }
        }
        g0[idx] = a0; g1[idx] = a1;
    }
    __syncthreads();
    float acc[64];
    #pragma unroll
    for (int o = 0; o < 64; o++) acc[o] = 0.f;
    int ty = threadIdx.x >> 4, tx = threadIdx.x & 15;
    for (int ci = 0; ci < 64; ci++) {
        float t0 = tok2[(b * NC + 0) * C + ci];   // uniform -> s_load
        float t1 = tok2[(b * NC + 1) * C + ci];
        for (int idx = threadIdx.x; idx < 324; idx += 256)
            til[idx] = g0[idx] * t0 + g1[idx] * t1;
        __syncthreads();
        float v[9];
        #pragma unroll
        for (int dy = 0; dy < 3; dy++)
            #pragma unroll
            for (int dx = 0; dx < 3; dx++)
                v[dy * 3 + dx] = til[(ty + dy) * 18 + (tx + dx)];
        #pragma unroll
        for (int oc = 0; oc < 64; oc++) {
            const float* wp = Ws + (oc * 64 + ci) * 9;   // uniform -> s_load
            float a = acc[oc];
            a += wp[0] * v[0]; a += wp[1] * v[1]; a += wp[2] * v[2];
            a += wp[3] * v[3]; a += wp[4] * v[4]; a += wp[5] * v[5];
            a += wp[6] * v[6]; a += wp[7] * v[7]; a += wp[8] * v[8];
            acc[oc] = a;
        }
        __syncthreads();
    }
    int py = ty0 + ty, px = tx0 + tx;
    #pragma unroll
    for (int oc = 0; oc < 64; oc++)
        y[(b * C + oc) * P + py * WWD + px] = acc[oc];
}

// K6: BN partial stats (fp64 accumulate) per channel
__global__ void k_stats(const float* __restrict__ y, double* __restrict__ st) {
    int ch = blockIdx.x, b = blockIdx.y;
    const float* yp = y + (b * C + ch) * P;
    double s = 0.0, s2 = 0.0;
    for (int p = threadIdx.x; p < P; p += 256) {
        double v = (double)yp[p];
        s += v; s2 += v * v;
    }
    for (int off = 32; off > 0; off >>= 1) { s += __shfl_down(s, off); s2 += __shfl_down(s2, off); }
    __shared__ double rs[4], rs2[4];
    int lane = threadIdx.x & 63, wave = threadIdx.x >> 6;
    if (lane == 0) { rs[wave] = s; rs2[wave] = s2; }
    __syncthreads();
    if (threadIdx.x == 0) {
        atomicAdd(&st[ch],      rs[0] + rs[1] + rs[2] + rs[3]);
        atomicAdd(&st[64 + ch], rs2[0] + rs2[1] + rs2[2] + rs2[3]);
    }
}

// K7: finalize BN scale/shift
__global__ void k_bnfin(const double* __restrict__ st, const float* __restrict__ gamma,
                        const float* __restrict__ beta, float* __restrict__ scale,
                        float* __restrict__ shift) {
    int c2 = threadIdx.x;
    double n = (double)(B * P);
    double mean = st[c2] / n;
    double var = st[64 + c2] / n - mean * mean;
    float sc = gamma[c2] * rsqrtf((float)var + 1e-5f);
    scale[c2] = sc;
    shift[c2] = beta[c2] - (float)mean * sc;
}

// K8: out = x + relu(y*scale+shift), in-place on d_out (y staged there), float4
__global__ void k_final(const float* __restrict__ x, const float* __restrict__ scale,
                        const float* __restrict__ shift, float* __restrict__ out) {
    int i4 = blockIdx.x * 256 + threadIdx.x;
    int base = i4 * 4;
    int ch = (base / P) % C;              // uniform per block (P % 1024 == 0)
    float sc = scale[ch], sh = shift[ch];
    float4 xv = *(const float4*)(x + base);
    float4 yv = *(float4*)(out + base);
    yv.x = fmaxf(yv.x * sc + sh, 0.f) + xv.x;
    yv.y = fmaxf(yv.y * sc + sh, 0.f) + xv.y;
    yv.z = fmaxf(yv.z * sc + sh, 0.f) + xv.z;
    yv.w = fmaxf(yv.w * sc + sh, 0.f) + xv.w;
    *(float4*)(out + base) = yv;
}

extern "C" void kernel_launch(void* const* d_in, const int* in_sizes, int n_in,
                              void* d_out, int out_size, void* d_ws, size_t ws_size,
                              hipStream_t stream) {
    const float* x     = (const float*)d_in[0];
    const float* cs    = (const float*)d_in[1];
    const float* Wc    = (const float*)d_in[2];
    const float* Wxs   = (const float*)d_in[3];
    const float* Wcsp  = (const float*)d_in[4];
    const float* Wcval = (const float*)d_in[5];
    const float* Wattn = (const float*)d_in[6];
    const float* Wcomb = (const float*)d_in[7];
    const float* Wsing = (const float*)d_in[8];
    const float* gamma = (const float*)d_in[9];
    const float* beta  = (const float*)d_in[10];
    float* ws  = (float*)d_ws;
    float* out = (float*)d_out;

    float*  space = ws + OFF_SPACE;
    float*  S     = ws + OFF_S;
    float*  R     = ws + OFF_R;
    float*  tok2  = ws + OFF_TOK2;
    double* st    = (double*)(ws + OFF_STATS);
    float*  scale = ws + OFF_SCALE;
    float*  shift = ws + OFF_SHIFT;

    // zero accumulators (S, tok2, stats, scale/shift) — ws is poisoned each call
    hipMemsetAsync(S, 0, (WS_FLOATS - OFF_S) * sizeof(float), stream);

    k_space<<<dim3(144, 16), 256, 0, stream>>>(cs, Wc, space, S);
    k_R2   <<<dim3(8, 8, 8), 256, 0, stream>>>(x, space, R);
    k_tok2 <<<dim3(16, 8), 64, 0, stream>>>(Wxs, Wcsp, R, S, tok2);
    k_conv <<<dim3(144, 8), 256, 0, stream>>>(cs, tok2, Wcval, Wattn, Wcomb, Wsing, out);
    k_stats<<<dim3(64, 8), 256, 0, stream>>>(out, st);
    k_bnfin<<<1, 64, 0, stream>>>(st, gamma, beta, scale, shift);
    k_final<<<(B * C * P) / 1024, 256, 0, stream>>>(x, scale, shift, out);
}

// Round 3
// 806.906 us; speedup vs baseline: 3.1857x; 1.8049x over previous
//
#include <hip/hip_runtime.h>
#include <math.h>

// Problem constants (fixed by reference setup_inputs)
#define B   8
#define C   64
#define HH  192
#define WWD 192
#define P   (HH*WWD)     // 36864
#define NC  2
#define NS  8

// Workspace layout (float offsets)
#define OFF_SPACE 0                    // 16*8*P = 4718592 unnormalized space maps
#define OFF_S     4718592              // 128 per-map sums
#define OFF_R     4718720              // 8*16*64*9 = 73728 correlations
#define OFF_TOK2  4792448              // 8*2*64 = 1024
#define OFF_U     4793472              // 8*64*2*9 = 9216 collapsed conv weights
#define OFF_STATS 4802688              // 128 doubles (256 float slots), 8B aligned
#define OFF_SCALE 4802944              // 64
#define OFF_SHIFT 4803008              // 64
#define WS_FLOATS 4803072              // ~19.2 MB total

__device__ __forceinline__ float sigm(float x) { return 1.0f / (1.0f + expf(-x)); }

// K1: space maps (sigmoid + 1->7 ch 3x3 conv + sigmoid), unnormalized, plus per-(map,ch) sums.
__global__ void k_space(const float* __restrict__ cs, const float* __restrict__ Wc,
                        float* __restrict__ space, float* __restrict__ S) {
    int m = blockIdx.y;                       // m = b*2 + c
    int p = blockIdx.x * 256 + threadIdx.x;   // 144*256 == P exactly
    int h = p / WWD, w = p - (p / WWD) * WWD;
    float cp[9];
    #pragma unroll
    for (int ky = 0; ky < 3; ky++)
        #pragma unroll
        for (int kx = 0; kx < 3; kx++) {
            int hh = h + ky - 1, ww = w + kx - 1;
            float v = 0.f;  // zero-pad AFTER sigmoid (conv pads class_prob with 0)
            if ((unsigned)hh < HH && (unsigned)ww < WWD)
                v = sigm(cs[m * P + hh * WWD + ww]);
            cp[ky * 3 + kx] = v;
        }
    float ch[8];
    ch[0] = cp[4];
    #pragma unroll
    for (int j = 0; j < 7; j++) {
        float a = 0.f;
        #pragma unroll
        for (int k = 0; k < 9; k++) a += Wc[j * 9 + k] * cp[k];
        ch[j + 1] = sigm(a);
    }
    #pragma unroll
    for (int q = 0; q < 8; q++)
        space[(m * 8 + q) * P + p] = ch[q];
    // per-(m,ch) spatial sums: wave reduce + atomic
    #pragma unroll
    for (int q = 0; q < 8; q++) {
        float v = ch[q];
        for (int off = 32; off > 0; off >>= 1) v += __shfl_down(v, off);
        if ((threadIdx.x & 63) == 0) atomicAdd(&S[m * 8 + q], v);
    }
}

// K2: register-tiled correlation.
// Block = (b, scg, ig): 2 space maps x 8 x-channels, full image per block.
__launch_bounds__(256, 2)
__global__ void k_R2(const float* __restrict__ x, const float* __restrict__ space,
                     float* __restrict__ R) {
    int ig  = blockIdx.x;   // 0..7 : i = ig*8 + il
    int scg = blockIdx.y;   // 0..7 : sc = scg*2 + m
    int b   = blockIdx.z;

    const float* xb = x + (b * C + ig * 8) * P;
    const float* spb[2];
    #pragma unroll
    for (int m = 0; m < 2; m++) {
        int sc = scg * 2 + m;
        int s = sc >> 1, c = sc & 1;
        spb[m] = space + ((b * NC + c) * NS + s) * P;
    }

    float acc[2][8][9];
    #pragma unroll
    for (int m = 0; m < 2; m++)
        #pragma unroll
        for (int i = 0; i < 8; i++)
            #pragma unroll
            for (int t = 0; t < 9; t++) acc[m][i][t] = 0.f;

    for (int iter = 0; iter < P / 256; iter++) {
        int p = iter * 256 + threadIdx.x;
        int h = p / WWD, w = p - (p / WWD) * WWD;
        float xv[8];
        #pragma unroll
        for (int i = 0; i < 8; i++) xv[i] = xb[i * P + p];
        #pragma unroll
        for (int m = 0; m < 2; m++) {
            const float* sp = spb[m];
            #pragma unroll
            for (int ty = 0; ty < 3; ty++) {
                int sh = h - ty + 1;
                #pragma unroll
                for (int tx = 0; tx < 3; tx++) {
                    int sw = w - tx + 1;
                    bool ok = ((unsigned)sh < HH) & ((unsigned)sw < WWD);
                    int idx = ok ? (sh * WWD + sw) : 0;
                    float v = sp[idx];
                    v = ok ? v : 0.f;
                    #pragma unroll
                    for (int i = 0; i < 8; i++)
                        acc[m][i][ty * 3 + tx] += xv[i] * v;
                }
            }
        }
    }

    __shared__ float red[4][144];
    int lane = threadIdx.x & 63, wave = threadIdx.x >> 6;
    #pragma unroll
    for (int m = 0; m < 2; m++)
        #pragma unroll
        for (int i = 0; i < 8; i++)
            #pragma unroll
            for (int t = 0; t < 9; t++) {
                float v = acc[m][i][t];
                for (int off = 32; off > 0; off >>= 1) v += __shfl_down(v, off);
                if (lane == 0) red[wave][(m * 8 + i) * 9 + t] = v;
            }
    __syncthreads();
    if (threadIdx.x < 144) {
        int v_ = threadIdx.x;
        int m = v_ / 72, rem = v_ % 72;
        int i = rem / 9, t = rem % 9;
        float s = red[0][v_] + red[1][v_] + red[2][v_] + red[3][v_];
        int sc = scg * 2 + m;
        R[((b * 16 + sc) * 64 + (ig * 8 + i)) * 9 + t] = s;
    }
}

// K3: tok2[b,c,d] = sum_s Wcs[s]/S[b,c,s] * sum_{i,k} Wxs[s*64+d,i,k] * R[b,s,c,i,k]
__global__ void k_tok2(const float* __restrict__ Wxs, const float* __restrict__ Wcs,
                       const float* __restrict__ R, const float* __restrict__ S,
                       float* __restrict__ tok2) {
    int bc = blockIdx.x, s = blockIdx.y;
    int b = bc >> 1, c = bc & 1;
    int d = threadIdx.x;
    const float* Rp = R + ((b * 16 + s * 2 + c) * 64) * 9;   // i*9+k contiguous
    const float* Wp = Wxs + (s * C + d) * (C * 9);           // i*9+k contiguous
    float a = 0.f;
    for (int t = 0; t < C * 9; t++) a += Wp[t] * Rp[t];
    float val = a * Wcs[s] / S[(b * NC + c) * NS + s];
    atomicAdd(&tok2[bc * C + d], val);
}

// K4: collapse conv weights against tok2:  U[b][oc][m][t] = sum_ci Ws[oc,ci,t] * tok2[b,m,ci]
__global__ void k_U(const float* __restrict__ Ws, const float* __restrict__ tok2,
                    float* __restrict__ U) {
    int b = blockIdx.x, m = blockIdx.y, oc = threadIdx.x;
    const float* tp = tok2 + (b * NC + m) * C;
    float u[9];
    #pragma unroll
    for (int t = 0; t < 9; t++) u[t] = 0.f;
    for (int ci = 0; ci < C; ci++) {
        float tv = tp[ci];
        const float* wp = Ws + (oc * C + ci) * 9;
        #pragma unroll
        for (int t = 0; t < 9; t++) u[t] += wp[t] * tv;
    }
    float* up = U + ((b * C + oc) * 2 + m) * 9;
    #pragma unroll
    for (int t = 0; t < 9; t++) up[t] = u[t];
}

// Shared staging: g0/g1 34x34 halo tiles (stride 35 to break bank conflicts)
__device__ __forceinline__ void stage_g(const float* __restrict__ cs, int b, int ty0, int tx0,
                                        const float* __restrict__ Wcval,
                                        const float* __restrict__ Wattn,
                                        const float* __restrict__ Wcomb,
                                        float* h0, float* h1) {
    float wa[8], wt[8];
    #pragma unroll
    for (int s = 0; s < 8; s++) { wa[s] = Wcomb[s] * Wcval[s]; wt[s] = Wattn[s]; }
    for (int idx = threadIdx.x; idx < 34 * 34; idx += 256) {
        int i = idx / 34, j = idx - (idx / 34) * 34;
        int gy = ty0 - 1 + i, gx = tx0 - 1 + j;
        float a0 = 0.f, a1 = 0.f;
        if ((unsigned)gy < HH && (unsigned)gx < WWD) {
            int p = gy * WWD + gx;
            float c0 = sigm(cs[(b * NC + 0) * P + p]);
            float c1 = sigm(cs[(b * NC + 1) * P + p]);
            #pragma unroll
            for (int s = 0; s < 8; s++) {
                a0 += wa[s] * sigm(c0 * wt[s]);
                a1 += wa[s] * sigm(c1 * wt[s]);
            }
        }
        h0[i * 35 + j] = a0; h1[i * 35 + j] = a1;
    }
}

// K5: compute y on the fly (pair of 3x3 convs per oc) and accumulate BN stats. No y write.
__launch_bounds__(256)
__global__ void k_cs(const float* __restrict__ cs, const float* __restrict__ U,
                     const float* __restrict__ Wcval, const float* __restrict__ Wattn,
                     const float* __restrict__ Wcomb, double* __restrict__ st) {
    int tile = blockIdx.x, ocg = blockIdx.y, b = blockIdx.z;
    int ty0 = (tile / 6) * 32, tx0 = (tile % 6) * 32;
    __shared__ float h0[34 * 35], h1[34 * 35];
    stage_g(cs, b, ty0, tx0, Wcval, Wattn, Wcomb, h0, h1);
    __syncthreads();

    int w = __builtin_amdgcn_readfirstlane(threadIdx.x >> 6);
    int lane = threadIdx.x & 63;
    int oc0 = ocg * 8 + w * 2;
    float u0[2][9], u1[2][9];
    #pragma unroll
    for (int j = 0; j < 2; j++) {
        const float* up = U + ((b * C + oc0 + j) * 2) * 9;
        #pragma unroll
        for (int t = 0; t < 9; t++) { u0[j][t] = up[t]; u1[j][t] = up[9 + t]; }
    }
    float s1[2] = {0.f, 0.f}, s2[2] = {0.f, 0.f};
    for (int it = 0; it < 4; it++) {
        int row = it * 8 + (lane >> 3);
        int c0 = (lane & 7) * 4;
        float g0v[3][6], g1v[3][6];
        #pragma unroll
        for (int dy = 0; dy < 3; dy++)
            #pragma unroll
            for (int dx = 0; dx < 6; dx++) {
                g0v[dy][dx] = h0[(row + dy) * 35 + c0 + dx];
                g1v[dy][dx] = h1[(row + dy) * 35 + c0 + dx];
            }
        #pragma unroll
        for (int j = 0; j < 2; j++)
            #pragma unroll
            for (int px = 0; px < 4; px++) {
                float y = 0.f;
                #pragma unroll
                for (int ky = 0; ky < 3; ky++)
                    #pragma unroll
                    for (int kx = 0; kx < 3; kx++) {
                        y += u0[j][ky * 3 + kx] * g0v[ky][px + kx];
                        y += u1[j][ky * 3 + kx] * g1v[ky][px + kx];
                    }
                s1[j] += y; s2[j] += y * y;
            }
    }
    #pragma unroll
    for (int j = 0; j < 2; j++) {
        float a = s1[j], q = s2[j];
        for (int off = 32; off > 0; off >>= 1) { a += __shfl_down(a, off); q += __shfl_down(q, off); }
        if (lane == 0) {
            atomicAdd(&st[oc0 + j], (double)a);
            atomicAdd(&st[64 + oc0 + j], (double)q);
        }
    }
}

// K6: finalize BN scale/shift
__global__ void k_bnfin(const double* __restrict__ st, const float* __restrict__ gamma,
                        const float* __restrict__ beta, float* __restrict__ scale,
                        float* __restrict__ shift) {
    int c2 = threadIdx.x;
    double n = (double)(B * P);
    double mean = st[c2] / n;
    double var = st[64 + c2] / n - mean * mean;
    float sc = gamma[c2] * rsqrtf((float)var + 1e-5f);
    scale[c2] = sc;
    shift[c2] = beta[c2] - (float)mean * sc;
}

// K7: recompute y, out = x + relu(y*scale+shift)
__launch_bounds__(256)
__global__ void k_fin2(const float* __restrict__ cs, const float* __restrict__ U,
                       const float* __restrict__ Wcval, const float* __restrict__ Wattn,
                       const float* __restrict__ Wcomb, const float* __restrict__ x,
                       const float* __restrict__ scale, const float* __restrict__ shift,
                       float* __restrict__ out) {
    int tile = blockIdx.x, ocg = blockIdx.y, b = blockIdx.z;
    int ty0 = (tile / 6) * 32, tx0 = (tile % 6) * 32;
    __shared__ float h0[34 * 35], h1[34 * 35];
    stage_g(cs, b, ty0, tx0, Wcval, Wattn, Wcomb, h0, h1);
    __syncthreads();

    int w = __builtin_amdgcn_readfirstlane(threadIdx.x >> 6);
    int lane = threadIdx.x & 63;
    int oc0 = ocg * 8 + w * 2;
    float u0[2][9], u1[2][9], sc[2], sh[2];
    #pragma unroll
    for (int j = 0; j < 2; j++) {
        const float* up = U + ((b * C + oc0 + j) * 2) * 9;
        #pragma unroll
        for (int t = 0; t < 9; t++) { u0[j][t] = up[t]; u1[j][t] = up[9 + t]; }
        sc[j] = scale[oc0 + j]; sh[j] = shift[oc0 + j];
    }
    for (int it = 0; it < 4; it++) {
        int row = it * 8 + (lane >> 3);
        int c0 = (lane & 7) * 4;
        float g0v[3][6], g1v[3][6];
        #pragma unroll
        for (int dy = 0; dy < 3; dy++)
            #pragma unroll
            for (int dx = 0; dx < 6; dx++) {
                g0v[dy][dx] = h0[(row + dy) * 35 + c0 + dx];
                g1v[dy][dx] = h1[(row + dy) * 35 + c0 + dx];
            }
        #pragma unroll
        for (int j = 0; j < 2; j++) {
            float y4[4];
            #pragma unroll
            for (int px = 0; px < 4; px++) {
                float y = 0.f;
                #pragma unroll
                for (int ky = 0; ky < 3; ky++)
                    #pragma unroll
                    for (int kx = 0; kx < 3; kx++) {
                        y += u0[j][ky * 3 + kx] * g0v[ky][px + kx];
                        y += u1[j][ky * 3 + kx] * g1v[ky][px + kx];
                    }
                y4[px] = y;
            }
            int ga = (b * C + oc0 + j) * P + (ty0 + row) * WWD + tx0 + c0;
            float4 xv = *(const float4*)(x + ga);
            float4 ov;
            ov.x = fmaxf(y4[0] * sc[j] + sh[j], 0.f) + xv.x;
            ov.y = fmaxf(y4[1] * sc[j] + sh[j], 0.f) + xv.y;
            ov.z = fmaxf(y4[2] * sc[j] + sh[j], 0.f) + xv.z;
            ov.w = fmaxf(y4[3] * sc[j] + sh[j], 0.f) + xv.w;
            *(float4*)(out + ga) = ov;
        }
    }
}

extern "C" void kernel_launch(void* const* d_in, const int* in_sizes, int n_in,
                              void* d_out, int out_size, void* d_ws, size_t ws_size,
                              hipStream_t stream) {
    const float* x     = (const float*)d_in[0];
    const float* cs    = (const float*)d_in[1];
    const float* Wc    = (const float*)d_in[2];
    const float* Wxs   = (const float*)d_in[3];
    const float* Wcsp  = (const float*)d_in[4];
    const float* Wcval = (const float*)d_in[5];
    const float* Wattn = (const float*)d_in[6];
    const float* Wcomb = (const float*)d_in[7];
    const float* Wsing = (const float*)d_in[8];
    const float* gamma = (const float*)d_in[9];
    const float* beta  = (const float*)d_in[10];
    float* ws  = (float*)d_ws;
    float* out = (float*)d_out;

    float*  space = ws + OFF_SPACE;
    float*  S     = ws + OFF_S;
    float*  R     = ws + OFF_R;
    float*  tok2  = ws + OFF_TOK2;
    float*  U     = ws + OFF_U;
    double* st    = (double*)(ws + OFF_STATS);
    float*  scale = ws + OFF_SCALE;
    float*  shift = ws + OFF_SHIFT;

    // zero accumulators (S, tok2, U, stats, scale/shift) — ws is poisoned each call
    hipMemsetAsync(S, 0, (WS_FLOATS - OFF_S) * sizeof(float), stream);

    k_space<<<dim3(144, 16), 256, 0, stream>>>(cs, Wc, space, S);
    k_R2   <<<dim3(8, 8, 8), 256, 0, stream>>>(x, space, R);
    k_tok2 <<<dim3(16, 8), 64, 0, stream>>>(Wxs, Wcsp, R, S, tok2);
    k_U    <<<dim3(8, 2), 64, 0, stream>>>(Wsing, tok2, U);
    k_cs   <<<dim3(36, 8, 8), 256, 0, stream>>>(cs, U, Wcval, Wattn, Wcomb, st);
    k_bnfin<<<1, 64, 0, stream>>>(st, gamma, beta, scale, shift);
    k_fin2 <<<dim3(36, 8, 8), 256, 0, stream>>>(cs, U, Wcval, Wattn, Wcomb, x, scale, shift, out);
}

// Round 4
// 486.100 us; speedup vs baseline: 5.2881x; 1.6600x over previous
//
#include <hip/hip_runtime.h>
#include <math.h>

// Problem constants (fixed by reference setup_inputs)
#define B   8
#define C   64
#define HH  192
#define WWD 192
#define P   (HH*WWD)     // 36864
#define NC  2
#define NS  8
#define PP  (194*194)    // padded space map (1-px zero halo), 37636

// Workspace layout (float offsets)
#define OFF_SPACE 0                    // 128 maps * PP = 4817408 (zero-padded)
#define OFF_SPART 4817408              // 128*144 per-block S partials
#define OFF_R     4835840              // 8*16*64*9 = 73728 correlations
#define OFF_TOK2  4909568              // 8*2*64 = 1024 (atomic accumulated, needs zero)
#define OFF_U     4910592              // 8*64*2*9 = 9216 collapsed conv weights
#define OFF_STP   4919808              // 2*64*288 BN partial sums
#define OFF_SCALE 4956672              // 64
#define OFF_SHIFT 4956736              // 64
#define WS_FLOATS 4956800              // ~19.8 MB total

__device__ __forceinline__ float sigm(float x) { return 1.0f / (1.0f + expf(-x)); }

// K1: space maps (sigmoid + 1->7 ch 3x3 conv + sigmoid) into zero-padded layout,
// plus per-(map,ch) per-block partial sums (NO global atomics).
__global__ void k_space(const float* __restrict__ cs, const float* __restrict__ Wc,
                        float* __restrict__ spp, float* __restrict__ Spart) {
    int m = blockIdx.y;                       // m = b*2 + c
    int bx = blockIdx.x;
    int p = bx * 256 + threadIdx.x;           // 144*256 == P exactly
    int h = p / WWD, w = p - (p / WWD) * WWD;
    float cp[9];
    #pragma unroll
    for (int ky = 0; ky < 3; ky++)
        #pragma unroll
        for (int kx = 0; kx < 3; kx++) {
            int hh = h + ky - 1, ww = w + kx - 1;
            float v = 0.f;  // zero-pad AFTER sigmoid (conv pads class_prob with 0)
            if ((unsigned)hh < HH && (unsigned)ww < WWD)
                v = sigm(cs[m * P + hh * WWD + ww]);
            cp[ky * 3 + kx] = v;
        }
    float ch[8];
    ch[0] = cp[4];
    #pragma unroll
    for (int j = 0; j < 7; j++) {
        float a = 0.f;
        #pragma unroll
        for (int k = 0; k < 9; k++) a += Wc[j * 9 + k] * cp[k];
        ch[j + 1] = sigm(a);
    }
    #pragma unroll
    for (int q = 0; q < 8; q++)
        spp[(m * 8 + q) * PP + (h + 1) * 194 + (w + 1)] = ch[q];
    // per-wave shfl reduce -> LDS -> per-block partial (no atomics)
    __shared__ float red[4][8];
    int lane = threadIdx.x & 63, wave = threadIdx.x >> 6;
    #pragma unroll
    for (int q = 0; q < 8; q++) {
        float v = ch[q];
        for (int off = 32; off > 0; off >>= 1) v += __shfl_down(v, off);
        if (lane == 0) red[wave][q] = v;
    }
    __syncthreads();
    if (threadIdx.x < 8) {
        int q = threadIdx.x;
        Spart[(m * 8 + q) * 144 + bx] = red[0][q] + red[1][q] + red[2][q] + red[3][q];
    }
}

// K2: register-tiled correlation, one space map x 8 x-channels per block.
// Padded space -> branchless shifted loads; 4 px/thread with float4 x loads.
__launch_bounds__(256, 3)
__global__ void k_R2(const float* __restrict__ x, const float* __restrict__ spp,
                     float* __restrict__ R) {
    int ig = blockIdx.x;    // 0..7 : i = ig*8 + il
    int sc = blockIdx.y;    // 0..15 : sc = s*2 + c
    int b  = blockIdx.z;
    int s = sc >> 1, c = sc & 1;
    const float* xb = x + (b * C + ig * 8) * P;
    const float* sp = spp + ((b * NC + c) * NS + s) * PP;

    float acc[8][9];
    #pragma unroll
    for (int i = 0; i < 8; i++)
        #pragma unroll
        for (int t = 0; t < 9; t++) acc[i][t] = 0.f;

    for (int it = 0; it < P / 1024; it++) {
        int p0 = it * 1024 + threadIdx.x * 4;
        int h = p0 / WWD, w0 = p0 - (p0 / WWD) * WWD;
        float4 xv[8];
        #pragma unroll
        for (int i = 0; i < 8; i++) xv[i] = *(const float4*)(xb + i * P + p0);
        float g[3][6];
        #pragma unroll
        for (int ty = 0; ty < 3; ty++) {
            const float* rp = sp + (h + 2 - ty) * 194 + w0;
            #pragma unroll
            for (int cc = 0; cc < 6; cc++) g[ty][cc] = rp[cc];
        }
        #pragma unroll
        for (int ty = 0; ty < 3; ty++)
            #pragma unroll
            for (int tx = 0; tx < 3; tx++) {
                float g0 = g[ty][2 - tx], g1 = g[ty][3 - tx];
                float g2 = g[ty][4 - tx], g3 = g[ty][5 - tx];
                #pragma unroll
                for (int i = 0; i < 8; i++) {
                    float a = acc[i][ty * 3 + tx];
                    a += xv[i].x * g0; a += xv[i].y * g1;
                    a += xv[i].z * g2; a += xv[i].w * g3;
                    acc[i][ty * 3 + tx] = a;
                }
            }
    }

    __shared__ float red[4][72];
    int lane = threadIdx.x & 63, wave = threadIdx.x >> 6;
    #pragma unroll
    for (int i = 0; i < 8; i++)
        #pragma unroll
        for (int t = 0; t < 9; t++) {
            float v = acc[i][t];
            for (int off = 32; off > 0; off >>= 1) v += __shfl_down(v, off);
            if (lane == 0) red[wave][i * 9 + t] = v;
        }
    __syncthreads();
    if (threadIdx.x < 72) {
        int i = threadIdx.x / 9, t = threadIdx.x - (threadIdx.x / 9) * 9;
        float v = red[0][threadIdx.x] + red[1][threadIdx.x] +
                  red[2][threadIdx.x] + red[3][threadIdx.x];
        R[((b * 16 + sc) * 64 + (ig * 8 + i)) * 9 + t] = v;
    }
}

// K3: tok2[b,c,d] = sum_s Wcs[s]/S[b,c,s] * sum_{i,k} Wxs[s*64+d,i,k] * R[b,s,c,i,k]
// S reduced in-block from Spart (144 partials).
__global__ void k_tok2(const float* __restrict__ Wxs, const float* __restrict__ Wcs,
                       const float* __restrict__ R, const float* __restrict__ Spart,
                       float* __restrict__ tok2) {
    int bc = blockIdx.x, s = blockIdx.y;
    int d = threadIdx.x;
    const float* spp = Spart + (bc * 8 + s) * 144;
    float sv = 0.f;
    for (int k = d; k < 144; k += 64) sv += spp[k];
    #pragma unroll
    for (int msk = 32; msk >= 1; msk >>= 1) sv += __shfl_xor(sv, msk);

    const float* Rp = R + ((bc & 1) + ((bc >> 1) * 16 + s * 2)) * 64 * 9;
    const float* Wp = Wxs + (s * C + d) * (C * 9);
    float a = 0.f;
    for (int t = 0; t < C * 9; t++) a += Wp[t] * Rp[t];
    float val = a * Wcs[s] / sv;
    atomicAdd(&tok2[bc * C + d], val);   // 8K atomics over 1024 addrs — negligible
}

// K4: collapse conv weights against tok2:  U[b][oc][m][t] = sum_ci Ws[oc,ci,t] * tok2[b,m,ci]
__global__ void k_U(const float* __restrict__ Ws, const float* __restrict__ tok2,
                    float* __restrict__ U) {
    int b = blockIdx.x, m = blockIdx.y, oc = threadIdx.x;
    const float* tp = tok2 + (b * NC + m) * C;
    float u[9];
    #pragma unroll
    for (int t = 0; t < 9; t++) u[t] = 0.f;
    for (int ci = 0; ci < C; ci++) {
        float tv = tp[ci];
        const float* wp = Ws + (oc * C + ci) * 9;
        #pragma unroll
        for (int t = 0; t < 9; t++) u[t] += wp[t] * tv;
    }
    float* up = U + ((b * C + oc) * 2 + m) * 9;
    #pragma unroll
    for (int t = 0; t < 9; t++) up[t] = u[t];
}

// Shared staging: g0/g1 34x34 halo tiles (stride 35 to break bank conflicts)
__device__ __forceinline__ void stage_g(const float* __restrict__ cs, int b, int ty0, int tx0,
                                        const float* __restrict__ Wcval,
                                        const float* __restrict__ Wattn,
                                        const float* __restrict__ Wcomb,
                                        float* h0, float* h1) {
    float wa[8], wt[8];
    #pragma unroll
    for (int s = 0; s < 8; s++) { wa[s] = Wcomb[s] * Wcval[s]; wt[s] = Wattn[s]; }
    for (int idx = threadIdx.x; idx < 34 * 34; idx += 256) {
        int i = idx / 34, j = idx - (idx / 34) * 34;
        int gy = ty0 - 1 + i, gx = tx0 - 1 + j;
        float a0 = 0.f, a1 = 0.f;
        if ((unsigned)gy < HH && (unsigned)gx < WWD) {
            int p = gy * WWD + gx;
            float c0 = sigm(cs[(b * NC + 0) * P + p]);
            float c1 = sigm(cs[(b * NC + 1) * P + p]);
            #pragma unroll
            for (int s = 0; s < 8; s++) {
                a0 += wa[s] * sigm(c0 * wt[s]);
                a1 += wa[s] * sigm(c1 * wt[s]);
            }
        }
        h0[i * 35 + j] = a0; h1[i * 35 + j] = a1;
    }
}

// K5: compute y on the fly, per-block BN partials to unique slots (NO global atomics).
__launch_bounds__(256)
__global__ void k_cs(const float* __restrict__ cs, const float* __restrict__ U,
                     const float* __restrict__ Wcval, const float* __restrict__ Wattn,
                     const float* __restrict__ Wcomb, float* __restrict__ STp) {
    int tile = blockIdx.x, ocg = blockIdx.y, b = blockIdx.z;
    int ty0 = (tile / 6) * 32, tx0 = (tile % 6) * 32;
    __shared__ float h0[34 * 35], h1[34 * 35];
    stage_g(cs, b, ty0, tx0, Wcval, Wattn, Wcomb, h0, h1);
    __syncthreads();

    int w = __builtin_amdgcn_readfirstlane(threadIdx.x >> 6);
    int lane = threadIdx.x & 63;
    int oc0 = ocg * 8 + w * 2;
    float u0[2][9], u1[2][9];
    #pragma unroll
    for (int j = 0; j < 2; j++) {
        const float* up = U + ((b * C + oc0 + j) * 2) * 9;
        #pragma unroll
        for (int t = 0; t < 9; t++) { u0[j][t] = up[t]; u1[j][t] = up[9 + t]; }
    }
    float s1[2] = {0.f, 0.f}, s2[2] = {0.f, 0.f};
    for (int it = 0; it < 4; it++) {
        int row = it * 8 + (lane >> 3);
        int c0 = (lane & 7) * 4;
        float g0v[3][6], g1v[3][6];
        #pragma unroll
        for (int dy = 0; dy < 3; dy++)
            #pragma unroll
            for (int dx = 0; dx < 6; dx++) {
                g0v[dy][dx] = h0[(row + dy) * 35 + c0 + dx];
                g1v[dy][dx] = h1[(row + dy) * 35 + c0 + dx];
            }
        #pragma unroll
        for (int j = 0; j < 2; j++)
            #pragma unroll
            for (int px = 0; px < 4; px++) {
                float y = 0.f;
                #pragma unroll
                for (int ky = 0; ky < 3; ky++)
                    #pragma unroll
                    for (int kx = 0; kx < 3; kx++) {
                        y += u0[j][ky * 3 + kx] * g0v[ky][px + kx];
                        y += u1[j][ky * 3 + kx] * g1v[ky][px + kx];
                    }
                s1[j] += y; s2[j] += y * y;
            }
    }
    #pragma unroll
    for (int j = 0; j < 2; j++) {
        float a = s1[j], q = s2[j];
        for (int off = 32; off > 0; off >>= 1) { a += __shfl_down(a, off); q += __shfl_down(q, off); }
        if (lane == 0) {
            int slot = b * 36 + tile;
            STp[(oc0 + j) * 288 + slot] = a;
            STp[64 * 288 + (oc0 + j) * 288 + slot] = q;
        }
    }
}

// K6: finalize BN scale/shift from 288 per-block partials per channel (fp64 accumulate)
__global__ void k_bnfin(const float* __restrict__ STp, const float* __restrict__ gamma,
                        const float* __restrict__ beta, float* __restrict__ scale,
                        float* __restrict__ shift) {
    int oc = threadIdx.x;
    double s = 0.0, s2 = 0.0;
    for (int k = 0; k < 288; k++) {
        s  += (double)STp[oc * 288 + k];
        s2 += (double)STp[64 * 288 + oc * 288 + k];
    }
    double n = (double)(B * P);
    double mean = s / n;
    double var = s2 / n - mean * mean;
    float sc = gamma[oc] * rsqrtf((float)var + 1e-5f);
    scale[oc] = sc;
    shift[oc] = beta[oc] - (float)mean * sc;
}

// K7: recompute y, out = x + relu(y*scale+shift)
__launch_bounds__(256)
__global__ void k_fin2(const float* __restrict__ cs, const float* __restrict__ U,
                       const float* __restrict__ Wcval, const float* __restrict__ Wattn,
                       const float* __restrict__ Wcomb, const float* __restrict__ x,
                       const float* __restrict__ scale, const float* __restrict__ shift,
                       float* __restrict__ out) {
    int tile = blockIdx.x, ocg = blockIdx.y, b = blockIdx.z;
    int ty0 = (tile / 6) * 32, tx0 = (tile % 6) * 32;
    __shared__ float h0[34 * 35], h1[34 * 35];
    stage_g(cs, b, ty0, tx0, Wcval, Wattn, Wcomb, h0, h1);
    __syncthreads();

    int w = __builtin_amdgcn_readfirstlane(threadIdx.x >> 6);
    int lane = threadIdx.x & 63;
    int oc0 = ocg * 8 + w * 2;
    float u0[2][9], u1[2][9], sc[2], sh[2];
    #pragma unroll
    for (int j = 0; j < 2; j++) {
        const float* up = U + ((b * C + oc0 + j) * 2) * 9;
        #pragma unroll
        for (int t = 0; t < 9; t++) { u0[j][t] = up[t]; u1[j][t] = up[9 + t]; }
        sc[j] = scale[oc0 + j]; sh[j] = shift[oc0 + j];
    }
    for (int it = 0; it < 4; it++) {
        int row = it * 8 + (lane >> 3);
        int c0 = (lane & 7) * 4;
        float g0v[3][6], g1v[3][6];
        #pragma unroll
        for (int dy = 0; dy < 3; dy++)
            #pragma unroll
            for (int dx = 0; dx < 6; dx++) {
                g0v[dy][dx] = h0[(row + dy) * 35 + c0 + dx];
                g1v[dy][dx] = h1[(row + dy) * 35 + c0 + dx];
            }
        #pragma unroll
        for (int j = 0; j < 2; j++) {
            float y4[4];
            #pragma unroll
            for (int px = 0; px < 4; px++) {
                float y = 0.f;
                #pragma unroll
                for (int ky = 0; ky < 3; ky++)
                    #pragma unroll
                    for (int kx = 0; kx < 3; kx++) {
                        y += u0[j][ky * 3 + kx] * g0v[ky][px + kx];
                        y += u1[j][ky * 3 + kx] * g1v[ky][px + kx];
                    }
                y4[px] = y;
            }
            int ga = (b * C + oc0 + j) * P + (ty0 + row) * WWD + tx0 + c0;
            float4 xv = *(const float4*)(x + ga);
            float4 ov;
            ov.x = fmaxf(y4[0] * sc[j] + sh[j], 0.f) + xv.x;
            ov.y = fmaxf(y4[1] * sc[j] + sh[j], 0.f) + xv.y;
            ov.z = fmaxf(y4[2] * sc[j] + sh[j], 0.f) + xv.z;
            ov.w = fmaxf(y4[3] * sc[j] + sh[j], 0.f) + xv.w;
            *(float4*)(out + ga) = ov;
        }
    }
}

extern "C" void kernel_launch(void* const* d_in, const int* in_sizes, int n_in,
                              void* d_out, int out_size, void* d_ws, size_t ws_size,
                              hipStream_t stream) {
    const float* x     = (const float*)d_in[0];
    const float* cs    = (const float*)d_in[1];
    const float* Wc    = (const float*)d_in[2];
    const float* Wxs   = (const float*)d_in[3];
    const float* Wcsp  = (const float*)d_in[4];
    const float* Wcval = (const float*)d_in[5];
    const float* Wattn = (const float*)d_in[6];
    const float* Wcomb = (const float*)d_in[7];
    const float* Wsing = (const float*)d_in[8];
    const float* gamma = (const float*)d_in[9];
    const float* beta  = (const float*)d_in[10];
    float* ws  = (float*)d_ws;
    float* out = (float*)d_out;

    float* spp   = ws + OFF_SPACE;
    float* Spart = ws + OFF_SPART;
    float* R     = ws + OFF_R;
    float* tok2  = ws + OFF_TOK2;
    float* U     = ws + OFF_U;
    float* STp   = ws + OFF_STP;
    float* scale = ws + OFF_SCALE;
    float* shift = ws + OFF_SHIFT;

    // zero padded-space halos + tok2 accumulator (covers space..tok2 contiguously)
    hipMemsetAsync(ws, 0, (size_t)(OFF_TOK2 + 1024) * sizeof(float), stream);

    k_space<<<dim3(144, 16), 256, 0, stream>>>(cs, Wc, spp, Spart);
    k_R2   <<<dim3(8, 16, 8), 256, 0, stream>>>(x, spp, R);
    k_tok2 <<<dim3(16, 8), 64, 0, stream>>>(Wxs, Wcsp, R, Spart, tok2);
    k_U    <<<dim3(8, 2), 64, 0, stream>>>(Wsing, tok2, U);
    k_cs   <<<dim3(36, 8, 8), 256, 0, stream>>>(cs, U, Wcval, Wattn, Wcomb, STp);
    k_bnfin<<<1, 64, 0, stream>>>(STp, gamma, beta, scale, shift);
    k_fin2 <<<dim3(36, 8, 8), 256, 0, stream>>>(cs, U, Wcval, Wattn, Wcomb, x, scale, shift, out);
}